// Round 2
// baseline (1430.242 us; speedup 1.0000x reference)
//
#include <hip/hip_runtime.h>

#define N_NODES 50000
#define E_EDGES 262144

typedef __attribute__((ext_vector_type(8))) short bf16x8;
typedef __attribute__((ext_vector_type(4))) float f32x4;

union V16 { uint4 u; bf16x8 h; };

__device__ __forceinline__ unsigned rne_pack(float a, float b) {
  unsigned ua = __float_as_uint(a); ua += 0x7fffu + ((ua >> 16) & 1u);
  unsigned ub = __float_as_uint(b); ub += 0x7fffu + ((ub >> 16) & 1u);
  return (ua >> 16) | (ub & 0xffff0000u);
}
__device__ __forceinline__ float bflo(unsigned u) { return __uint_as_float(u << 16); }
__device__ __forceinline__ float bfhi(unsigned u) { return __uint_as_float(u & 0xffff0000u); }
// pack(a_even, b_odd) = (bits(a)>>16) | (bits(b)&0xffff0000) in ONE v_perm_b32
__device__ __forceinline__ unsigned perm_pack(float a, float b) {
  return __builtin_amdgcn_perm(__float_as_uint(b), __float_as_uint(a), 0x07060302u);
}

__device__ __forceinline__ void async_gather16(const void* gptr, void* lptr) {
  __builtin_amdgcn_global_load_lds(
      (const __attribute__((address_space(1))) void*)gptr,
      (__attribute__((address_space(3))) void*)lptr, 16, 0, 0);
}

// ---- prep: node_repr fp32 -> bf16 (RNE) ----
__global__ void cvt_node_kernel(const float* __restrict__ x, unsigned short* __restrict__ y) {
  int i = (blockIdx.x * 256 + threadIdx.x) * 8;
  float4 f0 = *(const float4*)(x + i);
  float4 f1 = *(const float4*)(x + i + 4);
  uint4 o;
  o.x = rne_pack(f0.x, f0.y);
  o.y = rne_pack(f0.z, f0.w);
  o.z = rne_pack(f1.x, f1.y);
  o.w = rne_pack(f1.z, f1.w);
  *(uint4*)(y + i) = o;
}

// ---- prep: W1 (1024x512 row-major in->out) -> W1pp bf16 [col][1024] with
// k' = step*128 + s*32 + c  (orig k = s*256 + step*32 + c), step=c_chunk/32 ----
__global__ void prep_w1pp_kernel(const float* __restrict__ w1, unsigned short* __restrict__ w1pp) {
  int t = blockIdx.x * 256 + threadIdx.x;  // 65536 threads
  int col = t & 511;
  int j = t >> 9;  // 0..127, covers k' = j*8 .. j*8+8
  int step = j >> 4, s = (j >> 2) & 3, cl0 = (j & 3) * 8;
  int k0 = s * 256 + step * 32 + cl0;
  float f[8];
#pragma unroll
  for (int i = 0; i < 8; ++i) f[i] = w1[(size_t)(k0 + i) * 512 + col];
  uint4 o;
  o.x = rne_pack(f[0], f[1]);
  o.y = rne_pack(f[2], f[3]);
  o.z = rne_pack(f[4], f[5]);
  o.w = rne_pack(f[6], f[7]);
  *(uint4*)(w1pp + (size_t)col * 1024 + j * 8) = o;
}

// ---- prep: out[e][c] = b2[c] ----
__global__ void init_out_kernel(float* __restrict__ out, const float* __restrict__ b2) {
  int i = blockIdx.x * 256 + threadIdx.x;
  float2 v; v.x = b2[0]; v.y = b2[1];
  *(float2*)(out + (size_t)i * 2) = v;
}

// build |i-j| packed bf16 (trunc), sign masked after pack
__device__ __forceinline__ bf16x8 build_absdiff(V16 i, V16 j) {
  const unsigned iw[4] = {i.u.x, i.u.y, i.u.z, i.u.w};
  const unsigned jw[4] = {j.u.x, j.u.y, j.u.z, j.u.w};
  unsigned r[4];
#pragma unroll
  for (int w = 0; w < 4; ++w) {
    float d0 = bflo(iw[w]) - bflo(jw[w]);
    float d1 = bfhi(iw[w]) - bfhi(jw[w]);
    r[w] = perm_pack(d0, d1) & 0x7fff7fffu;
  }
  V16 o; o.u = make_uint4(r[0], r[1], r[2], r[3]);
  return o.h;
}
// build i*j packed bf16 (trunc)
__device__ __forceinline__ bf16x8 build_prod(V16 i, V16 j) {
  const unsigned iw[4] = {i.u.x, i.u.y, i.u.z, i.u.w};
  const unsigned jw[4] = {j.u.x, j.u.y, j.u.z, j.u.w};
  unsigned r[4];
#pragma unroll
  for (int w = 0; w < 4; ++w) {
    float p0 = bflo(iw[w]) * bflo(jw[w]);
    float p1 = bfhi(iw[w]) * bfhi(jw[w]);
    r[w] = perm_pack(p0, p1);
  }
  V16 o; o.u = make_uint4(r[0], r[1], r[2], r[3]);
  return o.h;
}

// ---- main fused kernel ----
__global__ __launch_bounds__(256, 3) void edge_mlp_kernel(
    const unsigned short* __restrict__ nodeb,  // [50000][256] bf16
    const unsigned short* __restrict__ w1pp,   // [512][1024] bf16 rearranged
    const int* __restrict__ src,
    const int* __restrict__ dst,
    const float* __restrict__ b1,
    const float* __restrict__ w2,   // [512][2] fp32
    float* __restrict__ out) {      // [E][2] fp32, pre-init with b2
  __shared__ char smem[49152];  // [0,8K) hi  [8K,16K) hj  [16K,48K) B

  const int tid = threadIdx.x;
  const int wid = tid >> 6;
  const int lane = tid & 63;
  const int quad = lane >> 4;
  const int l16 = lane & 15;
  const int bx = blockIdx.x;
  const int m_idx = ((bx >> 5) << 3) + (bx & 7);  // sibling n-blocks same XCD
  const int n_idx = (bx >> 3) & 3;
  const int wave_m = wid >> 1;
  const int wave_n = wid & 1;
  const int row0 = m_idx * 128;
  const int wrow0 = row0 + wave_m * 64;
  const int n0 = n_idx * 128 + wave_n * 64;

  const char* nodeB = (const char*)nodeb;
  const char* w1B = (const char*)w1pp;

  // ---- staging: A slots u = e*4+q (16B each); wave wid covers u in [wid*128, +128), 2 calls
  const int eA0 = row0 + wid * 32 + (lane >> 2);
  const int eA1 = eA0 + 16;
  const unsigned qA = (unsigned)((lane & 3) << 4);
  const unsigned oi0 = ((unsigned)src[eA0] << 9) + qA;
  const unsigned oi1 = ((unsigned)src[eA1] << 9) + qA;
  const unsigned oj0 = ((unsigned)dst[eA0] << 9) + qA;
  const unsigned oj1 = ((unsigned)dst[eA1] << 9) + qA;
  // B: 2048 slots; call c: u = c*256 + wid*64 + lane; col=u>>4, m=u&15, chunk=m^(col&7)
  unsigned oB[8];
#pragma unroll
  for (int c = 0; c < 8; ++c) {
    int u = c * 256 + wid * 64 + lane;
    int col = u >> 4;
    int chunk = (u & 15) ^ (col & 7);
    oB[c] = (unsigned)(n_idx * 128 + col) * 2048u + (unsigned)chunk * 16u;
  }
  // LDS staging bases (wave-uniform)
  char* hiS = smem + wid * 2048;
  char* hjS = smem + 8192 + wid * 2048;
  char* bS = smem + 16384 + wid * 1024;  // + c*4096

  // ---- read bases ----
  const int aoff = ((wave_m * 64 + l16) * 4 + quad) * 16;  // + mt*1024
  const char* hiR = smem + aoff;
  const char* hjR = smem + 8192 + aoff;
  const char* bR[4];
#pragma unroll
  for (int s = 0; s < 4; ++s)
    bR[s] = smem + 16384 + wave_n * 16384 + l16 * 256 +
            ((((s << 2) | quad) ^ (l16 & 7)) << 4);  // + nt*4096

  f32x4 acc[4][4];
#pragma unroll
  for (int mt = 0; mt < 4; ++mt)
#pragma unroll
    for (int nt = 0; nt < 4; ++nt)
      acc[mt][nt] = (f32x4){0.f, 0.f, 0.f, 0.f};

#pragma unroll 1
  for (int step = 0; step < 8; ++step) {
    __syncthreads();  // prev step's LDS reads done
    const unsigned ao = (unsigned)step * 64u;
    async_gather16(nodeB + (oi0 + ao), hiS);
    async_gather16(nodeB + (oi1 + ao), hiS + 1024);
    async_gather16(nodeB + (oj0 + ao), hjS);
    async_gather16(nodeB + (oj1 + ao), hjS + 1024);
    const unsigned bo = (unsigned)step * 256u;
#pragma unroll
    for (int c = 0; c < 8; ++c)
      async_gather16(w1B + (oB[c] + bo), bS + c * 4096);
    __syncthreads();  // staging complete (vmcnt drained by barrier)

    V16 hi[4], hj[4];
#pragma unroll
    for (int mt = 0; mt < 4; ++mt) {
      hi[mt].u = *(const uint4*)(hiR + mt * 1024);
      hj[mt].u = *(const uint4*)(hjR + mt * 1024);
    }
#pragma unroll
    for (int s = 0; s < 4; ++s) {
      V16 bf[4];
#pragma unroll
      for (int nt = 0; nt < 4; ++nt) bf[nt].u = *(const uint4*)(bR[s] + nt * 4096);
#pragma unroll
      for (int mt = 0; mt < 4; ++mt) {
        bf16x8 af;
        if (s == 0) af = hi[mt].h;
        else if (s == 1) af = hj[mt].h;
        else if (s == 2) af = build_absdiff(hi[mt], hj[mt]);
        else af = build_prod(hi[mt], hj[mt]);
#pragma unroll
        for (int nt = 0; nt < 4; ++nt)
          acc[mt][nt] = __builtin_amdgcn_mfma_f32_16x16x32_bf16(af, bf[nt].h, acc[mt][nt], 0, 0, 0);
      }
    }
  }

  // ---- epilogue: bias + ReLU + W2, 16-lane shuffle reduce, atomic out ----
#pragma unroll
  for (int mt = 0; mt < 4; ++mt) {
    float pc0[4] = {0.f, 0.f, 0.f, 0.f};
    float pc1[4] = {0.f, 0.f, 0.f, 0.f};
#pragma unroll
    for (int nt = 0; nt < 4; ++nt) {
      int gc = n0 + nt * 16 + l16;
      float b1v = b1[gc];
      float w20 = w2[gc * 2 + 0];
      float w21 = w2[gc * 2 + 1];
#pragma unroll
      for (int r = 0; r < 4; ++r) {
        float v = fmaxf(acc[mt][nt][r] + b1v, 0.f);
        pc0[r] = fmaf(v, w20, pc0[r]);
        pc1[r] = fmaf(v, w21, pc1[r]);
      }
    }
#pragma unroll
    for (int r = 0; r < 4; ++r) {
      float s0 = pc0[r], s1 = pc1[r];
#pragma unroll
      for (int off = 1; off < 16; off <<= 1) {
        s0 += __shfl_xor(s0, off);
        s1 += __shfl_xor(s1, off);
      }
      int e = wrow0 + mt * 16 + quad * 4 + r;  // C/D: row = quad*4 + r
      if (l16 == 0) unsafeAtomicAdd(&out[(size_t)e * 2 + 0], s0);
      if (l16 == 1) unsafeAtomicAdd(&out[(size_t)e * 2 + 1], s1);
    }
  }
}

extern "C" void kernel_launch(void* const* d_in, const int* in_sizes, int n_in,
                              void* d_out, int out_size, void* d_ws, size_t ws_size,
                              hipStream_t stream) {
  const float* node = (const float*)d_in[0];
  const int* src = (const int*)d_in[1];
  const int* dst = (const int*)d_in[2];
  const float* W1 = (const float*)d_in[3];
  const float* b1 = (const float*)d_in[4];
  const float* W2 = (const float*)d_in[5];
  const float* b2 = (const float*)d_in[6];
  float* out = (float*)d_out;

  unsigned short* nodeb = (unsigned short*)d_ws;                    // 25,600,000 B
  unsigned short* w1pp = (unsigned short*)((char*)d_ws + 25600000); // 1,048,576 B

  cvt_node_kernel<<<6250, 256, 0, stream>>>(node, nodeb);
  prep_w1pp_kernel<<<256, 256, 0, stream>>>(W1, w1pp);
  init_out_kernel<<<1024, 256, 0, stream>>>(out, b2);
  edge_mlp_kernel<<<8192, 256, 0, stream>>>(nodeb, w1pp, src, dst, b1, W2, out);
}

// Round 3
// 823.549 us; speedup vs baseline: 1.7367x; 1.7367x over previous
//
#include <hip/hip_runtime.h>

#define N_NODES 50000
#define E_EDGES 262144

typedef __attribute__((ext_vector_type(8))) short bf16x8;
typedef __attribute__((ext_vector_type(4))) float f32x4;

union V16 { uint4 u; bf16x8 h; };

__device__ __forceinline__ unsigned rne_pack(float a, float b) {
  unsigned ua = __float_as_uint(a); ua += 0x7fffu + ((ua >> 16) & 1u);
  unsigned ub = __float_as_uint(b); ub += 0x7fffu + ((ub >> 16) & 1u);
  return (ua >> 16) | (ub & 0xffff0000u);
}
__device__ __forceinline__ float bflo(unsigned u) { return __uint_as_float(u << 16); }
__device__ __forceinline__ float bfhi(unsigned u) { return __uint_as_float(u & 0xffff0000u); }
// (bits(a)>>16) | (bits(b)&0xffff0000) in one v_perm_b32
__device__ __forceinline__ unsigned perm_pack(float a, float b) {
  return __builtin_amdgcn_perm(__float_as_uint(b), __float_as_uint(a), 0x07060302u);
}

// ---- prep: node_repr fp32 -> bf16 (RNE) ----
__global__ void cvt_node_kernel(const float* __restrict__ x, unsigned short* __restrict__ y) {
  int i = (blockIdx.x * 256 + threadIdx.x) * 8;
  float4 f0 = *(const float4*)(x + i);
  float4 f1 = *(const float4*)(x + i + 4);
  uint4 o;
  o.x = rne_pack(f0.x, f0.y);
  o.y = rne_pack(f0.z, f0.w);
  o.z = rne_pack(f1.x, f1.y);
  o.w = rne_pack(f1.z, f1.w);
  *(uint4*)(y + i) = o;
}

// ---- prep: W1 (1024x512, row-major in->out) -> W1T bf16 (512 rows x 1024 cols) ----
__global__ void prep_w1t_kernel(const float* __restrict__ w1, unsigned short* __restrict__ w1t) {
  int t = blockIdx.x * 256 + threadIdx.x;  // 65536 threads
  int n = t >> 7;               // 0..511
  int kc = (t & 127) << 3;      // 0..1016 step 8
  float f[8];
#pragma unroll
  for (int i = 0; i < 8; ++i) f[i] = w1[(size_t)(kc + i) * 512 + n];
  uint4 o;
  o.x = rne_pack(f[0], f[1]);
  o.y = rne_pack(f[2], f[3]);
  o.z = rne_pack(f[4], f[5]);
  o.w = rne_pack(f[6], f[7]);
  *(uint4*)(w1t + (size_t)n * 1024 + kc) = o;
}

// ---- prep: out[e][c] = b2[c] ----
__global__ void init_out_kernel(float* __restrict__ out, const float* __restrict__ b2) {
  int i = blockIdx.x * 256 + threadIdx.x;
  float2 v; v.x = b2[0]; v.y = b2[1];
  *(float2*)(out + (size_t)i * 2) = v;
}

// build |i-j| packed bf16 (trunc)
__device__ __forceinline__ bf16x8 build_absdiff(V16 i, V16 j) {
  const unsigned iw[4] = {i.u.x, i.u.y, i.u.z, i.u.w};
  const unsigned jw[4] = {j.u.x, j.u.y, j.u.z, j.u.w};
  unsigned r[4];
#pragma unroll
  for (int w = 0; w < 4; ++w) {
    float d0 = bflo(iw[w]) - bflo(jw[w]);
    float d1 = bfhi(iw[w]) - bfhi(jw[w]);
    r[w] = perm_pack(d0, d1) & 0x7fff7fffu;
  }
  V16 o; o.u = make_uint4(r[0], r[1], r[2], r[3]);
  return o.h;
}
// build i*j packed bf16 (trunc)
__device__ __forceinline__ bf16x8 build_prod(V16 i, V16 j) {
  const unsigned iw[4] = {i.u.x, i.u.y, i.u.z, i.u.w};
  const unsigned jw[4] = {j.u.x, j.u.y, j.u.z, j.u.w};
  unsigned r[4];
#pragma unroll
  for (int w = 0; w < 4; ++w) {
    float p0 = bflo(iw[w]) * bflo(jw[w]);
    float p1 = bfhi(iw[w]) * bfhi(jw[w]);
    r[w] = perm_pack(p0, p1);
  }
  V16 o; o.u = make_uint4(r[0], r[1], r[2], r[3]);
  return o.h;
}

// ---- main fused kernel: software-pipelined, register-only (no LDS, no occupancy cap) ----
__global__ __launch_bounds__(256) void edge_mlp_kernel(
    const unsigned short* __restrict__ nodeb,  // [50000][256] bf16
    const unsigned short* __restrict__ w1t,    // [512][1024]  bf16 (W1^T)
    const int* __restrict__ src,
    const int* __restrict__ dst,
    const float* __restrict__ b1,
    const float* __restrict__ w2,   // [512][2] fp32
    float* __restrict__ out) {      // [E][2] fp32, pre-init with b2
  const int tid = threadIdx.x;
  const int wid = tid >> 6;
  const int lane = tid & 63;
  const int quad = lane >> 4;
  const int l16 = lane & 15;
  const int bx = blockIdx.x;
  // swizzle: 4 sibling n-blocks of one m-tile land on the same XCD (bx % 8)
  const int m_idx = ((bx >> 5) << 3) + (bx & 7);   // 0..2047
  const int n_idx = (bx >> 3) & 3;                 // 0..3
  const int wave_m = wid >> 1;
  const int wave_n = wid & 1;
  const int wrow0 = m_idx * 128 + wave_m * 64;
  const int n0 = n_idx * 128 + wave_n * 64;

  const char* nodeB = (const char*)nodeb;
  const char* w1tB = (const char*)w1t;

  // 32-bit byte offsets (node table = 25.6 MB, w1t = 1 MB)
  unsigned oi[4], oj[4];
#pragma unroll
  for (int mt = 0; mt < 4; ++mt) {
    int e = wrow0 + mt * 16 + l16;
    oi[mt] = ((unsigned)src[e] << 9) + (unsigned)(quad << 4);
    oj[mt] = ((unsigned)dst[e] << 9) + (unsigned)(quad << 4);
  }
  unsigned oB[4];
#pragma unroll
  for (int nt = 0; nt < 4; ++nt)
    oB[nt] = ((unsigned)(n0 + nt * 16 + l16) << 11) + (unsigned)(quad << 4);

  f32x4 acc[4][4];
#pragma unroll
  for (int mt = 0; mt < 4; ++mt)
#pragma unroll
    for (int nt = 0; nt < 4; ++nt)
      acc[mt][nt] = (f32x4){0.f, 0.f, 0.f, 0.f};

  // preload chunk 0 A-fragments
  V16 hiC[4], hjC[4];
#pragma unroll
  for (int mt = 0; mt < 4; ++mt) {
    hiC[mt].u = *(const uint4*)(nodeB + oi[mt]);
    hjC[mt].u = *(const uint4*)(nodeB + oj[mt]);
  }

  unsigned ao = 0;
#pragma unroll 1
  for (int t = 0; t < 8; ++t) {
    const unsigned aoN = (ao + 64u) & 511u;  // wraps at tail (harmless reload of chunk 0)
    // 1) all B loads for this chunk — single joined wait, overlaps build VALU
    V16 bf[4][4];
#pragma unroll
    for (int s = 0; s < 4; ++s)
#pragma unroll
      for (int nt = 0; nt < 4; ++nt)
        bf[s][nt].u = *(const uint4*)(w1tB + (oB[nt] + ao) + s * 512);
    // 2) A-gather prefetch for next chunk — in flight across the whole compute
    V16 hiN[4], hjN[4];
#pragma unroll
    for (int mt = 0; mt < 4; ++mt) {
      hiN[mt].u = *(const uint4*)(nodeB + (oi[mt] + aoN));
      hjN[mt].u = *(const uint4*)(nodeB + (oj[mt] + aoN));
    }
    // 3) compute on current chunk
#pragma unroll
    for (int s = 0; s < 4; ++s) {
#pragma unroll
      for (int mt = 0; mt < 4; ++mt) {
        bf16x8 af;
        if (s == 0) af = hiC[mt].h;
        else if (s == 1) af = hjC[mt].h;
        else if (s == 2) af = build_absdiff(hiC[mt], hjC[mt]);
        else af = build_prod(hiC[mt], hjC[mt]);
#pragma unroll
        for (int nt = 0; nt < 4; ++nt)
          acc[mt][nt] = __builtin_amdgcn_mfma_f32_16x16x32_bf16(af, bf[s][nt].h, acc[mt][nt], 0, 0, 0);
      }
    }
    // 4) rotate
#pragma unroll
    for (int mt = 0; mt < 4; ++mt) { hiC[mt] = hiN[mt]; hjC[mt] = hjN[mt]; }
    ao = aoN;
  }

  // ---- epilogue: bias + ReLU + W2, 16-lane shuffle reduce, atomic out ----
#pragma unroll
  for (int mt = 0; mt < 4; ++mt) {
    float pc0[4] = {0.f, 0.f, 0.f, 0.f};
    float pc1[4] = {0.f, 0.f, 0.f, 0.f};
#pragma unroll
    for (int nt = 0; nt < 4; ++nt) {
      int gc = n0 + nt * 16 + l16;
      float b1v = b1[gc];
      float w20 = w2[gc * 2 + 0];
      float w21 = w2[gc * 2 + 1];
#pragma unroll
      for (int r = 0; r < 4; ++r) {
        float v = fmaxf(acc[mt][nt][r] + b1v, 0.f);
        pc0[r] = fmaf(v, w20, pc0[r]);
        pc1[r] = fmaf(v, w21, pc1[r]);
      }
    }
#pragma unroll
    for (int r = 0; r < 4; ++r) {
      float s0 = pc0[r], s1 = pc1[r];
#pragma unroll
      for (int off = 1; off < 16; off <<= 1) {
        s0 += __shfl_xor(s0, off);
        s1 += __shfl_xor(s1, off);
      }
      int e = wrow0 + mt * 16 + quad * 4 + r;  // C/D: row = quad*4 + r
      if (l16 == 0) unsafeAtomicAdd(&out[(size_t)e * 2 + 0], s0);
      if (l16 == 1) unsafeAtomicAdd(&out[(size_t)e * 2 + 1], s1);
    }
  }
}

extern "C" void kernel_launch(void* const* d_in, const int* in_sizes, int n_in,
                              void* d_out, int out_size, void* d_ws, size_t ws_size,
                              hipStream_t stream) {
  const float* node = (const float*)d_in[0];
  const int* src = (const int*)d_in[1];
  const int* dst = (const int*)d_in[2];
  const float* W1 = (const float*)d_in[3];
  const float* b1 = (const float*)d_in[4];
  const float* W2 = (const float*)d_in[5];
  const float* b2 = (const float*)d_in[6];
  float* out = (float*)d_out;

  unsigned short* nodeb = (unsigned short*)d_ws;                    // 25,600,000 B
  unsigned short* w1t = (unsigned short*)((char*)d_ws + 25600000);  // 1,048,576 B

  cvt_node_kernel<<<6250, 256, 0, stream>>>(node, nodeb);
  prep_w1t_kernel<<<256, 256, 0, stream>>>(W1, w1t);
  init_out_kernel<<<1024, 256, 0, stream>>>(out, b2);
  edge_mlp_kernel<<<8192, 256, 0, stream>>>(nodeb, w1t, src, dst, b1, W2, out);
}

// Round 4
// 687.332 us; speedup vs baseline: 2.0809x; 1.1982x over previous
//
#include <hip/hip_runtime.h>

#define N_NODES 50000
#define E_EDGES 262144

typedef __attribute__((ext_vector_type(8))) short bf16x8;
typedef __attribute__((ext_vector_type(4))) float f32x4;

union V16 { uint4 u; bf16x8 h; };

__device__ __forceinline__ unsigned rne_pack(float a, float b) {
  unsigned ua = __float_as_uint(a); ua += 0x7fffu + ((ua >> 16) & 1u);
  unsigned ub = __float_as_uint(b); ub += 0x7fffu + ((ub >> 16) & 1u);
  return (ua >> 16) | (ub & 0xffff0000u);
}
__device__ __forceinline__ float bflo(unsigned u) { return __uint_as_float(u << 16); }
__device__ __forceinline__ float bfhi(unsigned u) { return __uint_as_float(u & 0xffff0000u); }
// (bits(a)>>16) | (bits(b)&0xffff0000) in one v_perm_b32
__device__ __forceinline__ unsigned perm_pack(float a, float b) {
  return __builtin_amdgcn_perm(__float_as_uint(b), __float_as_uint(a), 0x07060302u);
}
__device__ __forceinline__ void async_gather16(const void* gptr, void* lptr) {
  __builtin_amdgcn_global_load_lds(
      (const __attribute__((address_space(1))) void*)gptr,
      (__attribute__((address_space(3))) void*)lptr, 16, 0, 0);
}

// ---- prep: node_repr fp32 -> bf16 (RNE) ----
__global__ void cvt_node_kernel(const float* __restrict__ x, unsigned short* __restrict__ y) {
  int i = (blockIdx.x * 256 + threadIdx.x) * 8;
  float4 f0 = *(const float4*)(x + i);
  float4 f1 = *(const float4*)(x + i + 4);
  uint4 o;
  o.x = rne_pack(f0.x, f0.y);
  o.y = rne_pack(f0.z, f0.w);
  o.z = rne_pack(f1.x, f1.y);
  o.w = rne_pack(f1.z, f1.w);
  *(uint4*)(y + i) = o;
}

// ---- prep: W1 (1024x512 row-major in->out) -> W1pp2 bf16, 16-B units laid out
// [step(8)][sq=s*4+quad(16)][col(512)], unit = W1[k0..k0+8)[col], k0=s*256+step*32+quad*8
__global__ void prep_w1pp2_kernel(const float* __restrict__ w1, unsigned short* __restrict__ w1pp2) {
  int t = blockIdx.x * 256 + threadIdx.x;  // 65536 units
  int step = t >> 13;
  int rem = t & 8191;
  int sq = rem >> 9;
  int col = rem & 511;
  int s = sq >> 2, qd = sq & 3;
  int k0 = s * 256 + step * 32 + qd * 8;
  float f[8];
#pragma unroll
  for (int i = 0; i < 8; ++i) f[i] = w1[(size_t)(k0 + i) * 512 + col];
  uint4 o;
  o.x = rne_pack(f[0], f[1]);
  o.y = rne_pack(f[2], f[3]);
  o.z = rne_pack(f[4], f[5]);
  o.w = rne_pack(f[6], f[7]);
  *(uint4*)(w1pp2 + (size_t)t * 8) = o;
}

// ---- prep: out[e][c] = b2[c] ----
__global__ void init_out_kernel(float* __restrict__ out, const float* __restrict__ b2) {
  int i = blockIdx.x * 256 + threadIdx.x;
  float2 v; v.x = b2[0]; v.y = b2[1];
  *(float2*)(out + (size_t)i * 2) = v;
}

// build |i-j| packed bf16 (trunc)
__device__ __forceinline__ bf16x8 build_absdiff(V16 i, V16 j) {
  const unsigned iw[4] = {i.u.x, i.u.y, i.u.z, i.u.w};
  const unsigned jw[4] = {j.u.x, j.u.y, j.u.z, j.u.w};
  unsigned r[4];
#pragma unroll
  for (int w = 0; w < 4; ++w) {
    float d0 = bflo(iw[w]) - bflo(jw[w]);
    float d1 = bfhi(iw[w]) - bfhi(jw[w]);
    r[w] = perm_pack(d0, d1) & 0x7fff7fffu;
  }
  V16 o; o.u = make_uint4(r[0], r[1], r[2], r[3]);
  return o.h;
}
// build i*j packed bf16 (trunc)
__device__ __forceinline__ bf16x8 build_prod(V16 i, V16 j) {
  const unsigned iw[4] = {i.u.x, i.u.y, i.u.z, i.u.w};
  const unsigned jw[4] = {j.u.x, j.u.y, j.u.z, j.u.w};
  unsigned r[4];
#pragma unroll
  for (int w = 0; w < 4; ++w) {
    float p0 = bflo(iw[w]) * bflo(jw[w]);
    float p1 = bfhi(iw[w]) * bfhi(jw[w]);
    r[w] = perm_pack(p0, p1);
  }
  V16 o; o.u = make_uint4(r[0], r[1], r[2], r[3]);
  return o.h;
}

// ---- main fused kernel: m97-style 2-barrier K-loop, async global->LDS staging ----
__global__ __launch_bounds__(256) void edge_mlp_kernel(
    const unsigned short* __restrict__ nodeb,  // [50000][256] bf16
    const unsigned short* __restrict__ w1pp2,  // repacked W1 (see prep)
    const int* __restrict__ src,
    const int* __restrict__ dst,
    const float* __restrict__ b1,
    const float* __restrict__ w2,   // [512][2] fp32
    float* __restrict__ out) {      // [E][2] fp32, pre-init with b2
  // [0,8K) hi  [8K,16K) hj  [16K,48K) B
  __shared__ char smem[49152];

  const int tid = threadIdx.x;
  const int wid = tid >> 6;
  const int lane = tid & 63;
  const int quad = lane >> 4;
  const int l16 = lane & 15;
  const int bx = blockIdx.x;
  const int m_idx = ((bx >> 5) << 3) + (bx & 7);  // sibling n-blocks -> same XCD
  const int n_idx = (bx >> 3) & 3;
  const int wave_m = wid >> 1;
  const int wave_n = wid & 1;
  const int row0 = m_idx * 128;
  const int wrow0 = row0 + wave_m * 64;
  const int n0 = n_idx * 128 + wave_n * 64;

  const char* nodeB = (const char*)nodeb;
  const char* w1B = (const char*)w1pp2;

  // ---- stager state ----
  // A unit u (16B): e = u>>2, quad_phys = u&3, quad = quad_phys ^ ((e>>1)&3)
  const int eh = tid >> 2;  // local edge for call c: e = c*64 + eh
  const unsigned qsw = (unsigned)(((tid & 3) ^ ((tid >> 3) & 3)) << 4);
  const unsigned oi0 = ((unsigned)src[row0 + eh] << 9) + qsw;
  const unsigned oi1 = ((unsigned)src[row0 + 64 + eh] << 9) + qsw;
  const unsigned oj0 = ((unsigned)dst[row0 + eh] << 9) + qsw;
  const unsigned oj1 = ((unsigned)dst[row0 + 64 + eh] << 9) + qsw;
  // B global base: unit u = c*256+tid -> off = (u>>7)*8192 + n_idx*2048 + (u&127)*16
  const unsigned bB0 = (unsigned)((tid >> 7) * 8192 + n_idx * 2048 + (tid & 127) * 16);
  // LDS staging dests (wave-uniform base + lane*16)
  char* hiS = smem + wid * 1024;          // + c*4096
  char* hjS = smem + 8192 + wid * 1024;   // + c*4096
  char* bS = smem + 16384 + wid * 1024;   // + c*4096

  // ---- reader bases ----
  const unsigned aR = (unsigned)((wave_m * 64 + l16) * 64 + ((quad ^ ((l16 >> 1) & 3)) << 4));
  const unsigned bR = (unsigned)(quad * 2048 + (wave_n * 64 + l16) * 16);

  f32x4 acc[4][4];
#pragma unroll
  for (int mt = 0; mt < 4; ++mt)
#pragma unroll
    for (int nt = 0; nt < 4; ++nt)
      acc[mt][nt] = (f32x4){0.f, 0.f, 0.f, 0.f};

#pragma unroll 1
  for (int step = 0; step < 8; ++step) {
    __syncthreads();  // readers done with previous chunk
    const unsigned ao = (unsigned)step * 64u;
    async_gather16(nodeB + (oi0 + ao), hiS);
    async_gather16(nodeB + (oi1 + ao), hiS + 4096);
    async_gather16(nodeB + (oj0 + ao), hjS);
    async_gather16(nodeB + (oj1 + ao), hjS + 4096);
    const char* wsrc = w1B + (unsigned)step * 131072u + bB0;
#pragma unroll
    for (int c = 0; c < 8; ++c)
      async_gather16(wsrc + c * 16384, bS + c * 4096);
    __syncthreads();  // staging complete (vmcnt drained before barrier)

    V16 hi[4], hj[4];
#pragma unroll
    for (int mt = 0; mt < 4; ++mt) {
      hi[mt].u = *(const uint4*)(smem + aR + mt * 1024);
      hj[mt].u = *(const uint4*)(smem + 8192 + aR + mt * 1024);
    }
#pragma unroll
    for (int s = 0; s < 4; ++s) {
      V16 bf[4];
#pragma unroll
      for (int nt = 0; nt < 4; ++nt)
        bf[nt].u = *(const uint4*)(smem + 16384 + bR + s * 8192 + nt * 256);
#pragma unroll
      for (int mt = 0; mt < 4; ++mt) {
        bf16x8 af;
        if (s == 0) af = hi[mt].h;
        else if (s == 1) af = hj[mt].h;
        else if (s == 2) af = build_absdiff(hi[mt], hj[mt]);
        else af = build_prod(hi[mt], hj[mt]);
#pragma unroll
        for (int nt = 0; nt < 4; ++nt)
          acc[mt][nt] = __builtin_amdgcn_mfma_f32_16x16x32_bf16(af, bf[nt].h, acc[mt][nt], 0, 0, 0);
      }
    }
  }

  // ---- epilogue: bias + ReLU + W2, 16-lane shuffle reduce, atomic out ----
#pragma unroll
  for (int mt = 0; mt < 4; ++mt) {
    float pc0[4] = {0.f, 0.f, 0.f, 0.f};
    float pc1[4] = {0.f, 0.f, 0.f, 0.f};
#pragma unroll
    for (int nt = 0; nt < 4; ++nt) {
      int gc = n0 + nt * 16 + l16;
      float b1v = b1[gc];
      float w20 = w2[gc * 2 + 0];
      float w21 = w2[gc * 2 + 1];
#pragma unroll
      for (int r = 0; r < 4; ++r) {
        float v = fmaxf(acc[mt][nt][r] + b1v, 0.f);
        pc0[r] = fmaf(v, w20, pc0[r]);
        pc1[r] = fmaf(v, w21, pc1[r]);
      }
    }
#pragma unroll
    for (int r = 0; r < 4; ++r) {
      float s0 = pc0[r], s1 = pc1[r];
#pragma unroll
      for (int off = 1; off < 16; off <<= 1) {
        s0 += __shfl_xor(s0, off);
        s1 += __shfl_xor(s1, off);
      }
      int e = wrow0 + mt * 16 + quad * 4 + r;  // C/D: row = quad*4 + r
      if (l16 == 0) unsafeAtomicAdd(&out[(size_t)e * 2 + 0], s0);
      if (l16 == 1) unsafeAtomicAdd(&out[(size_t)e * 2 + 1], s1);
    }
  }
}

extern "C" void kernel_launch(void* const* d_in, const int* in_sizes, int n_in,
                              void* d_out, int out_size, void* d_ws, size_t ws_size,
                              hipStream_t stream) {
  const float* node = (const float*)d_in[0];
  const int* src = (const int*)d_in[1];
  const int* dst = (const int*)d_in[2];
  const float* W1 = (const float*)d_in[3];
  const float* b1 = (const float*)d_in[4];
  const float* W2 = (const float*)d_in[5];
  const float* b2 = (const float*)d_in[6];
  float* out = (float*)d_out;

  unsigned short* nodeb = (unsigned short*)d_ws;                      // 25,600,000 B
  unsigned short* w1pp2 = (unsigned short*)((char*)d_ws + 25600000);  // 1,048,576 B

  cvt_node_kernel<<<6250, 256, 0, stream>>>(node, nodeb);
  prep_w1pp2_kernel<<<256, 256, 0, stream>>>(W1, w1pp2);
  init_out_kernel<<<1024, 256, 0, stream>>>(out, b2);
  edge_mlp_kernel<<<8192, 256, 0, stream>>>(nodeb, w1pp2, src, dst, b1, W2, out);
}

// Round 5
// 484.040 us; speedup vs baseline: 2.9548x; 1.4200x over previous
//
#include <hip/hip_runtime.h>

#define N_NODES 50000
#define E_EDGES 262144

typedef __attribute__((ext_vector_type(8))) short bf16x8;
typedef __attribute__((ext_vector_type(4))) float f32x4;

union V16 { uint4 u; bf16x8 h; };

__device__ __forceinline__ unsigned rne_pack(float a, float b) {
  unsigned ua = __float_as_uint(a); ua += 0x7fffu + ((ua >> 16) & 1u);
  unsigned ub = __float_as_uint(b); ub += 0x7fffu + ((ub >> 16) & 1u);
  return (ua >> 16) | (ub & 0xffff0000u);
}
__device__ __forceinline__ float bflo(unsigned u) { return __uint_as_float(u << 16); }
__device__ __forceinline__ float bfhi(unsigned u) { return __uint_as_float(u & 0xffff0000u); }
// (bits(a)>>16) | (bits(b)&0xffff0000) in one v_perm_b32
__device__ __forceinline__ unsigned perm_pack(float a, float b) {
  return __builtin_amdgcn_perm(__float_as_uint(b), __float_as_uint(a), 0x07060302u);
}
__device__ __forceinline__ void async_gather16(const void* gptr, void* lptr) {
  __builtin_amdgcn_global_load_lds(
      (const __attribute__((address_space(1))) void*)gptr,
      (__attribute__((address_space(3))) void*)lptr, 16, 0, 0);
}

// ---- prep: node_repr fp32 -> bf16 (RNE) ----
__global__ void cvt_node_kernel(const float* __restrict__ x, unsigned short* __restrict__ y) {
  int i = (blockIdx.x * 256 + threadIdx.x) * 8;
  float4 f0 = *(const float4*)(x + i);
  float4 f1 = *(const float4*)(x + i + 4);
  uint4 o;
  o.x = rne_pack(f0.x, f0.y);
  o.y = rne_pack(f0.z, f0.w);
  o.z = rne_pack(f1.x, f1.y);
  o.w = rne_pack(f1.z, f1.w);
  *(uint4*)(y + i) = o;
}

// ---- prep: W1 (1024x512 row-major in->out) -> W1pp2 bf16, 16-B units laid out
// [step(8)][sq=s*4+quad(16)][col(512)], unit = W1[k0..k0+8)[col], k0=s*256+step*32+quad*8
__global__ void prep_w1pp2_kernel(const float* __restrict__ w1, unsigned short* __restrict__ w1pp2) {
  int t = blockIdx.x * 256 + threadIdx.x;  // 65536 units
  int step = t >> 13;
  int rem = t & 8191;
  int sq = rem >> 9;
  int col = rem & 511;
  int s = sq >> 2, qd = sq & 3;
  int k0 = s * 256 + step * 32 + qd * 8;
  float f[8];
#pragma unroll
  for (int i = 0; i < 8; ++i) f[i] = w1[(size_t)(k0 + i) * 512 + col];
  uint4 o;
  o.x = rne_pack(f[0], f[1]);
  o.y = rne_pack(f[2], f[3]);
  o.z = rne_pack(f[4], f[5]);
  o.w = rne_pack(f[6], f[7]);
  *(uint4*)(w1pp2 + (size_t)t * 8) = o;
}

// ---- prep: out[e][c] = b2[c] ----
__global__ void init_out_kernel(float* __restrict__ out, const float* __restrict__ b2) {
  int i = blockIdx.x * 256 + threadIdx.x;
  float2 v; v.x = b2[0]; v.y = b2[1];
  *(float2*)(out + (size_t)i * 2) = v;
}

// ---- main fused kernel: double-buffered issue-before-compute pipeline ----
__global__ __launch_bounds__(256) void edge_mlp_kernel(
    const unsigned short* __restrict__ nodeb,  // [50000][256] bf16
    const unsigned short* __restrict__ w1pp2,  // repacked W1 (see prep)
    const int* __restrict__ src,
    const int* __restrict__ dst,
    const float* __restrict__ b1,
    const float* __restrict__ w2,   // [512][2] fp32
    float* __restrict__ out) {      // [E][2] fp32, pre-init with b2
  // Abuf p: [p*16K, p*16K+16K): hi 8K | hj 8K.  Bbuf0 @32K, Bbuf1 @48K (16K each: [sl][quad][col]*16B)
  __shared__ char smem[65536];

  const int tid = threadIdx.x;
  const int wid = tid >> 6;
  const int lane = tid & 63;
  const int quad = lane >> 4;
  const int l16 = lane & 15;
  const int bx = blockIdx.x;
  const int m_idx = ((bx >> 5) << 3) + (bx & 7);  // sibling n-blocks -> same XCD
  const int n_idx = (bx >> 3) & 3;
  const int wave_m = wid >> 1;
  const int wave_n = wid & 1;
  const int row0 = m_idx * 128;
  const int wrow0 = row0 + wave_m * 64;
  const int n0 = n_idx * 128 + wave_n * 64;

  const char* nodeB = (const char*)nodeb;
  const char* w1B = (const char*)w1pp2;

  // ---- A stager state: unit u=c*256+tid -> e=u>>2 (c*64 + tid>>2), phys quad = tid&3
  const int eh = tid >> 2;
  const unsigned qsw = (unsigned)(((tid & 3) ^ ((tid >> 3) & 3)) << 4);
  const unsigned oi0 = ((unsigned)src[row0 + eh] << 9) + qsw;
  const unsigned oi1 = ((unsigned)src[row0 + 64 + eh] << 9) + qsw;
  const unsigned oj0 = ((unsigned)dst[row0 + eh] << 9) + qsw;
  const unsigned oj1 = ((unsigned)dst[row0 + 64 + eh] << 9) + qsw;
  // ---- B stager state: per shalf, call c: s=shalf*2+(c>>1), qd=((tid>>7)+2c)&3
  const unsigned baset = (unsigned)((n_idx * 128 + (tid & 127)) * 16);
  unsigned bo0[4], bo1[4];
#pragma unroll
  for (int c = 0; c < 4; ++c) {
    unsigned sl = (unsigned)(c >> 1);
    unsigned qd = (unsigned)(((tid >> 7) + 2 * c) & 3);
    bo0[c] = ((sl * 4 + qd) * 8192u) + baset;
    bo1[c] = (((2 + sl) * 4 + qd) * 8192u) + baset;
  }
  const unsigned sdst = (unsigned)(wid * 1024);  // wave-uniform LDS dest offset
  char* Bb0 = smem + 32768;
  char* Bb1 = smem + 49152;

  // ---- reader bases ----
  const unsigned aR = (unsigned)((wave_m * 64 + l16) * 64 + ((quad ^ ((l16 >> 1) & 3)) << 4));
  const unsigned bR = (unsigned)(quad * 2048 + (wave_n * 64 + l16) * 16);

  f32x4 acc[4][4];
#pragma unroll
  for (int mt = 0; mt < 4; ++mt)
#pragma unroll
    for (int nt = 0; nt < 4; ++nt)
      acc[mt][nt] = (f32x4){0.f, 0.f, 0.f, 0.f};

  // ---- prologue: stage A(0)->Abuf0, B(0,shalf0)->Bb0 ----
  {
    char* A0 = smem;
    async_gather16(nodeB + oi0, A0 + sdst);
    async_gather16(nodeB + oi1, A0 + 4096 + sdst);
    async_gather16(nodeB + oj0, A0 + 8192 + sdst);
    async_gather16(nodeB + oj1, A0 + 12288 + sdst);
#pragma unroll
    for (int c = 0; c < 4; ++c)
      async_gather16(w1B + bo0[c], Bb0 + c * 4096 + sdst);
  }
  __syncthreads();

  int p = 0;
#pragma unroll 1
  for (int step = 0; step < 8; ++step) {
    const char* Acur = smem + (p << 14);
    const unsigned wstep = (unsigned)step * 131072u;
    // ===== h0: stage B(step,shalf1)->Bb1; compute s=0,1 from Acur,Bb0 =====
#pragma unroll
    for (int c = 0; c < 4; ++c)
      async_gather16(w1B + (wstep + bo1[c]), Bb1 + c * 4096 + sdst);

    V16 hi[4], hj[4];
#pragma unroll
    for (int mt = 0; mt < 4; ++mt) {
      hi[mt].u = *(const uint4*)(Acur + aR + mt * 1024);
      hj[mt].u = *(const uint4*)(Acur + 8192 + aR + mt * 1024);
    }
#pragma unroll
    for (int sl = 0; sl < 2; ++sl) {
      V16 bf[4];
#pragma unroll
      for (int nt = 0; nt < 4; ++nt)
        bf[nt].u = *(const uint4*)(Bb0 + sl * 8192 + bR + nt * 256);
#pragma unroll
      for (int mt = 0; mt < 4; ++mt) {
        bf16x8 af = (sl == 0) ? hi[mt].h : hj[mt].h;
#pragma unroll
        for (int nt = 0; nt < 4; ++nt)
          acc[mt][nt] = __builtin_amdgcn_mfma_f32_16x16x32_bf16(af, bf[nt].h, acc[mt][nt], 0, 0, 0);
      }
    }
    __syncthreads();  // Bb1 staged & Bb0 reads done

    // ===== h1: stage B(step+1,shalf0)->Bb0 + A(step+1)->Aalt; compute s=2,3 from Acur,Bb1 =====
    if (step < 7) {
      const unsigned aoN = (unsigned)(step + 1) * 64u;
      char* Aalt = smem + ((p ^ 1) << 14);
      async_gather16(nodeB + (oi0 + aoN), Aalt + sdst);
      async_gather16(nodeB + (oi1 + aoN), Aalt + 4096 + sdst);
      async_gather16(nodeB + (oj0 + aoN), Aalt + 8192 + sdst);
      async_gather16(nodeB + (oj1 + aoN), Aalt + 12288 + sdst);
      const unsigned wstepN = wstep + 131072u;
#pragma unroll
      for (int c = 0; c < 4; ++c)
        async_gather16(w1B + (wstepN + bo0[c]), Bb0 + c * 4096 + sdst);
    }
    // fused build: unpack hi/hj once, make a2 (|d|) and a3 (prod)
    V16 a2[4], a3[4];
#pragma unroll
    for (int mt = 0; mt < 4; ++mt) {
      const unsigned hw[4] = {hi[mt].u.x, hi[mt].u.y, hi[mt].u.z, hi[mt].u.w};
      const unsigned jw[4] = {hj[mt].u.x, hj[mt].u.y, hj[mt].u.z, hj[mt].u.w};
      unsigned d[4], pr[4];
#pragma unroll
      for (int w = 0; w < 4; ++w) {
        float i0 = bflo(hw[w]), i1 = bfhi(hw[w]);
        float j0 = bflo(jw[w]), j1 = bfhi(jw[w]);
        d[w] = perm_pack(i0 - j0, i1 - j1) & 0x7fff7fffu;
        pr[w] = perm_pack(i0 * j0, i1 * j1);
      }
      a2[mt].u = make_uint4(d[0], d[1], d[2], d[3]);
      a3[mt].u = make_uint4(pr[0], pr[1], pr[2], pr[3]);
    }
#pragma unroll
    for (int sl = 0; sl < 2; ++sl) {
      V16 bf[4];
#pragma unroll
      for (int nt = 0; nt < 4; ++nt)
        bf[nt].u = *(const uint4*)(Bb1 + sl * 8192 + bR + nt * 256);
#pragma unroll
      for (int mt = 0; mt < 4; ++mt) {
        bf16x8 af = (sl == 0) ? a2[mt].h : a3[mt].h;
#pragma unroll
        for (int nt = 0; nt < 4; ++nt)
          acc[mt][nt] = __builtin_amdgcn_mfma_f32_16x16x32_bf16(af, bf[nt].h, acc[mt][nt], 0, 0, 0);
      }
    }
    __syncthreads();  // Bb0/Aalt staged & Bb1/Acur reads done
    p ^= 1;
  }

  // ---- epilogue: bias + ReLU + W2, 16-lane shuffle reduce, atomic out ----
#pragma unroll
  for (int mt = 0; mt < 4; ++mt) {
    float pc0[4] = {0.f, 0.f, 0.f, 0.f};
    float pc1[4] = {0.f, 0.f, 0.f, 0.f};
#pragma unroll
    for (int nt = 0; nt < 4; ++nt) {
      int gc = n0 + nt * 16 + l16;
      float b1v = b1[gc];
      float w20 = w2[gc * 2 + 0];
      float w21 = w2[gc * 2 + 1];
#pragma unroll
      for (int r = 0; r < 4; ++r) {
        float v = fmaxf(acc[mt][nt][r] + b1v, 0.f);
        pc0[r] = fmaf(v, w20, pc0[r]);
        pc1[r] = fmaf(v, w21, pc1[r]);
      }
    }
#pragma unroll
    for (int r = 0; r < 4; ++r) {
      float s0 = pc0[r], s1 = pc1[r];
#pragma unroll
      for (int off = 1; off < 16; off <<= 1) {
        s0 += __shfl_xor(s0, off);
        s1 += __shfl_xor(s1, off);
      }
      int e = wrow0 + mt * 16 + quad * 4 + r;  // C/D: row = quad*4 + r
      if (l16 == 0) unsafeAtomicAdd(&out[(size_t)e * 2 + 0], s0);
      if (l16 == 1) unsafeAtomicAdd(&out[(size_t)e * 2 + 1], s1);
    }
  }
}

extern "C" void kernel_launch(void* const* d_in, const int* in_sizes, int n_in,
                              void* d_out, int out_size, void* d_ws, size_t ws_size,
                              hipStream_t stream) {
  const float* node = (const float*)d_in[0];
  const int* src = (const int*)d_in[1];
  const int* dst = (const int*)d_in[2];
  const float* W1 = (const float*)d_in[3];
  const float* b1 = (const float*)d_in[4];
  const float* W2 = (const float*)d_in[5];
  const float* b2 = (const float*)d_in[6];
  float* out = (float*)d_out;

  unsigned short* nodeb = (unsigned short*)d_ws;                      // 25,600,000 B
  unsigned short* w1pp2 = (unsigned short*)((char*)d_ws + 25600000);  // 1,048,576 B

  cvt_node_kernel<<<6250, 256, 0, stream>>>(node, nodeb);
  prep_w1pp2_kernel<<<256, 256, 0, stream>>>(W1, w1pp2);
  init_out_kernel<<<1024, 256, 0, stream>>>(out, b2);
  edge_mlp_kernel<<<8192, 256, 0, stream>>>(nodeb, w1pp2, src, dst, b1, W2, out);
}

// Round 6
// 472.866 us; speedup vs baseline: 3.0246x; 1.0236x over previous
//
#include <hip/hip_runtime.h>

#define N_NODES 50000
#define E_EDGES 262144

typedef __attribute__((ext_vector_type(8))) short bf16x8;
typedef __attribute__((ext_vector_type(4))) float f32x4;

union V16 { uint4 u; bf16x8 h; };

__device__ __forceinline__ unsigned rne_pack(float a, float b) {
  unsigned ua = __float_as_uint(a); ua += 0x7fffu + ((ua >> 16) & 1u);
  unsigned ub = __float_as_uint(b); ub += 0x7fffu + ((ub >> 16) & 1u);
  return (ua >> 16) | (ub & 0xffff0000u);
}
__device__ __forceinline__ float bflo(unsigned u) { return __uint_as_float(u << 16); }
__device__ __forceinline__ float bfhi(unsigned u) { return __uint_as_float(u & 0xffff0000u); }
// (bits(a)>>16) | (bits(b)&0xffff0000) in one v_perm_b32
__device__ __forceinline__ unsigned perm_pack(float a, float b) {
  return __builtin_amdgcn_perm(__float_as_uint(b), __float_as_uint(a), 0x07060302u);
}
__device__ __forceinline__ void async_gather16(const void* gptr, void* lptr) {
  __builtin_amdgcn_global_load_lds(
      (const __attribute__((address_space(1))) void*)gptr,
      (__attribute__((address_space(3))) void*)lptr, 16, 0, 0);
}

// ---- prep: node_repr fp32 -> bf16 (RNE) ----
__global__ void cvt_node_kernel(const float* __restrict__ x, unsigned short* __restrict__ y) {
  int i = (blockIdx.x * 256 + threadIdx.x) * 8;
  float4 f0 = *(const float4*)(x + i);
  float4 f1 = *(const float4*)(x + i + 4);
  uint4 o;
  o.x = rne_pack(f0.x, f0.y);
  o.y = rne_pack(f0.z, f0.w);
  o.z = rne_pack(f1.x, f1.y);
  o.w = rne_pack(f1.z, f1.w);
  *(uint4*)(y + i) = o;
}

// ---- prep: W1 (1024x512 row-major in->out) -> W1pp2 bf16, 16-B units laid out
// [step(8)][sq=s*4+quad(16)][col(512)], unit = W1[k0..k0+8)[col], k0=s*256+step*32+quad*8
__global__ void prep_w1pp2_kernel(const float* __restrict__ w1, unsigned short* __restrict__ w1pp2) {
  int t = blockIdx.x * 256 + threadIdx.x;  // 65536 units
  int step = t >> 13;
  int rem = t & 8191;
  int sq = rem >> 9;
  int col = rem & 511;
  int s = sq >> 2, qd = sq & 3;
  int k0 = s * 256 + step * 32 + qd * 8;
  float f[8];
#pragma unroll
  for (int i = 0; i < 8; ++i) f[i] = w1[(size_t)(k0 + i) * 512 + col];
  uint4 o;
  o.x = rne_pack(f[0], f[1]);
  o.y = rne_pack(f[2], f[3]);
  o.z = rne_pack(f[4], f[5]);
  o.w = rne_pack(f[6], f[7]);
  *(uint4*)(w1pp2 + (size_t)t * 8) = o;
}

// ---- prep: out[e][c] = b2[c] ----
__global__ void init_out_kernel(float* __restrict__ out, const float* __restrict__ b2) {
  int i = blockIdx.x * 256 + threadIdx.x;
  float2 v; v.x = b2[0]; v.y = b2[1];
  *(float2*)(out + (size_t)i * 2) = v;
}

// ---- main fused kernel: 1 barrier/step; A via LDS dbuf (full-step prefetch), B via registers ----
__global__ __launch_bounds__(256, 2) void edge_mlp_kernel(
    const unsigned short* __restrict__ nodeb,  // [50000][256] bf16
    const unsigned short* __restrict__ w1pp2,  // repacked W1 (see prep)
    const int* __restrict__ src,
    const int* __restrict__ dst,
    const float* __restrict__ b1,
    const float* __restrict__ w2,   // [512][2] fp32
    float* __restrict__ out) {      // [E][2] fp32, pre-init with b2
  // A buffers: buf p at [p*16K, p*16K+16K): hi 8K | hj 8K
  __shared__ char smem[32768];

  const int tid = threadIdx.x;
  const int wid = tid >> 6;
  const int lane = tid & 63;
  const int quad = lane >> 4;
  const int l16 = lane & 15;
  const int bx = blockIdx.x;
  const int m_idx = ((bx >> 5) << 3) + (bx & 7);  // sibling n-blocks -> same XCD
  const int n_idx = (bx >> 3) & 3;
  const int wave_m = wid >> 1;
  const int wave_n = wid & 1;
  const int row0 = m_idx * 128;
  const int wrow0 = row0 + wave_m * 64;
  const int n0 = n_idx * 128 + wave_n * 64;

  const char* nodeB = (const char*)nodeb;
  const char* w1B = (const char*)w1pp2;

  // ---- A stager state: unit u=c*256+tid -> e=u>>2, LDS slot holds global quad (tid&3)^((tid>>3)&3)
  const int eh = tid >> 2;
  const unsigned qsw = (unsigned)(((tid & 3) ^ ((tid >> 3) & 3)) << 4);
  const unsigned oi0 = ((unsigned)src[row0 + eh] << 9) + qsw;
  const unsigned oi1 = ((unsigned)src[row0 + 64 + eh] << 9) + qsw;
  const unsigned oj0 = ((unsigned)dst[row0 + eh] << 9) + qsw;
  const unsigned oj1 = ((unsigned)dst[row0 + 64 + eh] << 9) + qsw;
  const unsigned sdst = (unsigned)(wid * 1024);  // wave-uniform LDS dest offset

  // ---- B register-load offsets: (s*4+quad)*8192 + (nbase + nt*16 + l16)*16  (+ step*131072)
  unsigned bOff[4];
#pragma unroll
  for (int s = 0; s < 4; ++s)
    bOff[s] = (unsigned)((s * 4 + quad) * 8192 + (n0 + l16) * 16);

  // ---- A reader base ----
  const unsigned aR = (unsigned)((wave_m * 64 + l16) * 64 + ((quad ^ ((l16 >> 1) & 3)) << 4));

  f32x4 acc[4][4];
#pragma unroll
  for (int mt = 0; mt < 4; ++mt)
#pragma unroll
    for (int nt = 0; nt < 4; ++nt)
      acc[mt][nt] = (f32x4){0.f, 0.f, 0.f, 0.f};

  // ---- prologue: stage A(0) into buf0 ----
  async_gather16(nodeB + oi0, smem + sdst);
  async_gather16(nodeB + oi1, smem + 4096 + sdst);
  async_gather16(nodeB + oj0, smem + 8192 + sdst);
  async_gather16(nodeB + oj1, smem + 12288 + sdst);
  __syncthreads();

  int p = 0;
#pragma unroll 1
  for (int step = 0; step < 8; ++step) {
    const char* Acur = smem + (p << 14);
    // 1) A(step+1) gathers -> other buffer; drained at THIS step's end barrier (full-step flight)
    if (step < 7) {
      const unsigned aoN = (unsigned)(step + 1) * 64u;
      char* Aalt = smem + ((p ^ 1) << 14);
      async_gather16(nodeB + (oi0 + aoN), Aalt + sdst);
      async_gather16(nodeB + (oi1 + aoN), Aalt + 4096 + sdst);
      async_gather16(nodeB + (oj0 + aoN), Aalt + 8192 + sdst);
      async_gather16(nodeB + (oj1 + aoN), Aalt + 12288 + sdst);
    }
    // 2) B register loads for this step (L2-resident, consumed in s order before barrier)
    const unsigned wstep = (unsigned)step * 131072u;
    V16 bf[4][4];
#pragma unroll
    for (int s = 0; s < 4; ++s)
#pragma unroll
      for (int nt = 0; nt < 4; ++nt)
        bf[s][nt].u = *(const uint4*)(w1B + (wstep + bOff[s]) + nt * 256);
    // 3) A fragments from LDS (staged during step-1, guaranteed by prior barrier)
    V16 hi[4], hj[4];
#pragma unroll
    for (int mt = 0; mt < 4; ++mt) {
      hi[mt].u = *(const uint4*)(Acur + aR + mt * 1024);
      hj[mt].u = *(const uint4*)(Acur + 8192 + aR + mt * 1024);
    }
    // 4) compute: s=0 (hi), s=1 (hj), then build a2/a3 jointly, s=2,3
#pragma unroll
    for (int sl = 0; sl < 2; ++sl) {
#pragma unroll
      for (int mt = 0; mt < 4; ++mt) {
        bf16x8 af = (sl == 0) ? hi[mt].h : hj[mt].h;
#pragma unroll
        for (int nt = 0; nt < 4; ++nt)
          acc[mt][nt] = __builtin_amdgcn_mfma_f32_16x16x32_bf16(af, bf[sl][nt].h, acc[mt][nt], 0, 0, 0);
      }
    }
#pragma unroll
    for (int mt = 0; mt < 4; ++mt) {
      const unsigned hw[4] = {hi[mt].u.x, hi[mt].u.y, hi[mt].u.z, hi[mt].u.w};
      const unsigned jw[4] = {hj[mt].u.x, hj[mt].u.y, hj[mt].u.z, hj[mt].u.w};
      unsigned d[4], pr[4];
#pragma unroll
      for (int w = 0; w < 4; ++w) {
        float i0 = bflo(hw[w]), i1 = bfhi(hw[w]);
        float j0 = bflo(jw[w]), j1 = bfhi(jw[w]);
        d[w] = perm_pack(i0 - j0, i1 - j1) & 0x7fff7fffu;
        pr[w] = perm_pack(i0 * j0, i1 * j1);
      }
      V16 a2, a3;
      a2.u = make_uint4(d[0], d[1], d[2], d[3]);
      a3.u = make_uint4(pr[0], pr[1], pr[2], pr[3]);
#pragma unroll
      for (int nt = 0; nt < 4; ++nt)
        acc[mt][nt] = __builtin_amdgcn_mfma_f32_16x16x32_bf16(a2.h, bf[2][nt].h, acc[mt][nt], 0, 0, 0);
#pragma unroll
      for (int nt = 0; nt < 4; ++nt)
        acc[mt][nt] = __builtin_amdgcn_mfma_f32_16x16x32_bf16(a3.h, bf[3][nt].h, acc[mt][nt], 0, 0, 0);
    }
    __syncthreads();  // drains A(step+1) (full step in flight); LDS reads of Acur done block-wide
    p ^= 1;
  }

  // ---- epilogue: bias + ReLU + W2, 16-lane shuffle reduce, atomic out ----
#pragma unroll
  for (int mt = 0; mt < 4; ++mt) {
    float pc0[4] = {0.f, 0.f, 0.f, 0.f};
    float pc1[4] = {0.f, 0.f, 0.f, 0.f};
#pragma unroll
    for (int nt = 0; nt < 4; ++nt) {
      int gc = n0 + nt * 16 + l16;
      float b1v = b1[gc];
      float w20 = w2[gc * 2 + 0];
      float w21 = w2[gc * 2 + 1];
#pragma unroll
      for (int r = 0; r < 4; ++r) {
        float v = fmaxf(acc[mt][nt][r] + b1v, 0.f);
        pc0[r] = fmaf(v, w20, pc0[r]);
        pc1[r] = fmaf(v, w21, pc1[r]);
      }
    }
#pragma unroll
    for (int r = 0; r < 4; ++r) {
      float s0 = pc0[r], s1 = pc1[r];
#pragma unroll
      for (int off = 1; off < 16; off <<= 1) {
        s0 += __shfl_xor(s0, off);
        s1 += __shfl_xor(s1, off);
      }
      int e = wrow0 + mt * 16 + quad * 4 + r;  // C/D: row = quad*4 + r
      if (l16 == 0) unsafeAtomicAdd(&out[(size_t)e * 2 + 0], s0);
      if (l16 == 1) unsafeAtomicAdd(&out[(size_t)e * 2 + 1], s1);
    }
  }
}

extern "C" void kernel_launch(void* const* d_in, const int* in_sizes, int n_in,
                              void* d_out, int out_size, void* d_ws, size_t ws_size,
                              hipStream_t stream) {
  const float* node = (const float*)d_in[0];
  const int* src = (const int*)d_in[1];
  const int* dst = (const int*)d_in[2];
  const float* W1 = (const float*)d_in[3];
  const float* b1 = (const float*)d_in[4];
  const float* W2 = (const float*)d_in[5];
  const float* b2 = (const float*)d_in[6];
  float* out = (float*)d_out;

  unsigned short* nodeb = (unsigned short*)d_ws;                      // 25,600,000 B
  unsigned short* w1pp2 = (unsigned short*)((char*)d_ws + 25600000);  // 1,048,576 B

  cvt_node_kernel<<<6250, 256, 0, stream>>>(node, nodeb);
  prep_w1pp2_kernel<<<256, 256, 0, stream>>>(W1, w1pp2);
  init_out_kernel<<<1024, 256, 0, stream>>>(out, b2);
  edge_mlp_kernel<<<8192, 256, 0, stream>>>(nodeb, w1pp2, src, dst, b1, W2, out);
}